// Round 19
// baseline (51.145 us; speedup 1.0000x reference)
//
#include <hip/hip_runtime.h>
#include <hip/hip_bf16.h>

#define NF 262144      // C*H*W
#define NROWS 32       // batch
#define RSTRIDE 1152   // floats per block record: 1024 cross + 96 vec + pad
#define NBLK 2048
#define NKG 16

#define WS2_OFF (NBLK * RSTRIDE)   // 16 reduced slices of RSTRIDE

typedef __attribute__((ext_vector_type(8))) __bf16 bf16x8;
typedef __attribute__((ext_vector_type(16))) float f32x16;
typedef __attribute__((ext_vector_type(4)))  float f32x4v;   // asm-fenceable 128-bit vector

__device__ __forceinline__ float sigmoid_fast(float x) {
    float e = __expf(-x);
    return __builtin_amdgcn_rcpf(1.0f + e);
}

// ---------------- Fused pass: direct MFMA-fragment gather, full-vector liveness fence ----------------
// 2048 blocks x 4 waves; wave gw owns cols [gw*32, gw*32+32). Lane: row r=lane&31,
// k-half g=lane>>5. All 12 float4 loads batched; fence consumes FULL vectors so the
// compiler cannot component-split/re-sink them (R18's .x-only fence was defeated).
__global__ __launch_bounds__(256) void cl_fused(const float* __restrict__ in1,
                                                const float* __restrict__ in2,
                                                const float* __restrict__ msk,
                                                float* __restrict__ ws) {
    const int tid  = threadIdx.x;
    const int w    = tid >> 6;
    const int lane = tid & 63;
    const int r    = lane & 31;
    const int g    = lane >> 5;
    const int gw   = blockIdx.x * 4 + w;            // [0, 8192)
    const size_t rowoff = (size_t)r * NF;
    const int cbase = gw * 32 + g * 8;

    const float* p1 = in1 + rowoff + cbase;
    const float* p2 = in2 + rowoff + cbase;
    const float* pm = msk + rowoff + cbase;

    // ---- issue ALL 12 independent 16B loads (2 MFMA steps x 3 arrays x 2) ----
    f32x4v va[2][2], vb[2][2], vm[2][2];
    #pragma unroll
    for (int s = 0; s < 2; ++s) {
        va[s][0] = *(const f32x4v*)(p1 + s * 16);
        va[s][1] = *(const f32x4v*)(p1 + s * 16 + 4);
        vb[s][0] = *(const f32x4v*)(p2 + s * 16);
        vb[s][1] = *(const f32x4v*)(p2 + s * 16 + 4);
        vm[s][0] = *(const f32x4v*)(pm + s * 16);
        vm[s][1] = *(const f32x4v*)(pm + s * 16 + 4);
    }
    // Full-vector liveness fence: all 48 dwords must be materialized here.
    asm volatile("" :: "v"(va[0][0]), "v"(va[0][1]), "v"(va[1][0]), "v"(va[1][1]),
                       "v"(vb[0][0]), "v"(vb[0][1]), "v"(vb[1][0]), "v"(vb[1][1]),
                       "v"(vm[0][0]), "v"(vm[0][1]), "v"(vm[1][0]), "v"(vm[1][1]));

    f32x16 acc;
    #pragma unroll
    for (int k = 0; k < 16; ++k) acc[k] = 0.0f;
    float pos = 0.0f, q1 = 0.0f, q2 = 0.0f;

    #pragma unroll
    for (int s = 0; s < 2; ++s) {
        float xa[8], xb[8], xm[8];
        *(f32x4v*)&xa[0] = va[s][0]; *(f32x4v*)&xa[4] = va[s][1];
        *(f32x4v*)&xb[0] = vb[s][0]; *(f32x4v*)&xb[4] = vb[s][1];
        *(f32x4v*)&xm[0] = vm[s][0]; *(f32x4v*)&xm[4] = vm[s][1];

        bf16x8 fa, fb;
        #pragma unroll
        for (int e = 0; e < 8; ++e) {
            float sa = sigmoid_fast(xa[e]);
            float sb = sigmoid_fast(xb[e]);
            float d  = xm[e] * (sa - sb);
            pos = fmaf(d, d, pos);
            q1  = fmaf(sa, sa, q1);
            q2  = fmaf(sb, sb, q2);
            fa[e] = (__bf16)sa;
            fb[e] = (__bf16)sb;
        }
        acc = __builtin_amdgcn_mfma_f32_32x32x16_bf16(fa, fb, acc, 0, 0, 0);
    }

    // ---- atomic-free epilogue: per-wave private LDS regions (R7-verified) ----
    __shared__ float s_c[4096];   // 4 x 1024
    __shared__ float s_v[384];    // 4 x 96
    const int col = lane & 31;
    const int rhi = (lane >> 5) * 4;
    #pragma unroll
    for (int reg = 0; reg < 16; ++reg) {
        const int row = (reg & 3) + 8 * (reg >> 2) + rhi;   // verified C/D mapping
        s_c[w * 1024 + row * 32 + col] = acc[reg];
    }
    pos += __shfl_down(pos, 32);
    q1  += __shfl_down(q1, 32);
    q2  += __shfl_down(q2, 32);
    if (lane < 32) {
        s_v[w * 96 + r]      = pos;
        s_v[w * 96 + 32 + r] = q1;
        s_v[w * 96 + 64 + r] = q2;
    }
    __syncthreads();

    float* P = ws + (size_t)blockIdx.x * RSTRIDE;
    for (int idx = tid; idx < 1024; idx += 256)
        P[idx] = s_c[idx] + s_c[1024 + idx] + s_c[2048 + idx] + s_c[3072 + idx];
    if (tid < 96)
        P[1024 + tid] = s_v[tid] + s_v[96 + tid] + s_v[192 + tid] + s_v[288 + tid];
}

// Reduce 2048 records -> 16 slices; thread (kg, slot) sums 128 records (coalesced).
__global__ __launch_bounds__(256) void cl_reduce(const float* __restrict__ ws_ro,
                                                 float* __restrict__ ws) {
    const int kg   = blockIdx.x / 5;                        // 0..15
    const int slot = (blockIdx.x % 5) * 256 + threadIdx.x;  // 0..1279
    if (slot >= RSTRIDE) return;
    const float* base = ws_ro + (size_t)kg * 128 * RSTRIDE + slot;
    float s = 0.0f;
    #pragma unroll 8
    for (int k = 0; k < 128; ++k) s += base[(size_t)k * RSTRIDE];
    ws[WS2_OFF + kg * RSTRIDE + slot] = s;
}

__global__ __launch_bounds__(1024) void cl_final(const float* __restrict__ ws,
                                                 float* __restrict__ out) {
    __shared__ float s_loss[32];
    const int tid = threadIdx.x;
    const int i = tid >> 5, j = tid & 31;
    const float invN = 1.0f / (float)NF;

    float c = 0.0f, p = 0.0f, s1 = 0.0f, s2 = 0.0f;
    #pragma unroll
    for (int k = 0; k < NKG; ++k) {
        const float* sl = ws + WS2_OFF + (size_t)k * RSTRIDE;
        c  += sl[i * 32 + j];
        p  += sl[1024 + i];
        s1 += sl[1056 + i];
        s2 += sl[1088 + j];
    }

    float d = (s1 + s2 - 2.0f * c) * invN;
    float sim = (i == j) ? 0.0f : expf(-d * 10.0f);   // TAU = 0.1
    #pragma unroll
    for (int off = 16; off; off >>= 1) sim += __shfl_xor(sim, off);

    if (j == 0) {
        float sp = expf(-p * invN * 10.0f);
        s_loss[i] = -logf(sp / (sp + sim));
    }
    __syncthreads();
    if (tid == 0) {
        float t = 0.0f;
        #pragma unroll
        for (int k = 0; k < 32; ++k) t += s_loss[k];
        out[0] = t * (1.0f / 32.0f);
    }
}

extern "C" void kernel_launch(void* const* d_in, const int* in_sizes, int n_in,
                              void* d_out, int out_size, void* d_ws, size_t ws_size,
                              hipStream_t stream) {
    const float* in1 = (const float*)d_in[0];
    const float* in2 = (const float*)d_in[1];
    const float* msk = (const float*)d_in[2];
    float* out = (float*)d_out;
    float* ws  = (float*)d_ws;

    cl_fused <<<NBLK, 256, 0, stream>>>(in1, in2, msk, ws);
    cl_reduce<<<80,   256, 0, stream>>>(ws, ws);
    cl_final <<<1,   1024, 0, stream>>>(ws, out);
}

// Round 20
// 43.318 us; speedup vs baseline: 1.1807x; 1.1807x over previous
//
#include <hip/hip_runtime.h>
#include <hip/hip_bf16.h>

#define NF 262144     // C*H*W
#define NROWS 32      // batch
#define CSTRIDE 1088  // floats per cross partial record (1024 + pad, non-pow2)
#define NKG 16

// ws carve-up (floats): two row-major bf16 panels [32][NF] (16 MB each), then partials
#define PAN1_OFF 0
#define PAN2_OFF 4194304               // 16 MB / 4
#define CREC_OFF 8388608               // 32 MB / 4
#define WS2_OFF  (CREC_OFF + 1024 * CSTRIDE)
#define PQ_OFF   (WS2_OFF + NKG * CSTRIDE)   // 3 x [32][16] partials

typedef __attribute__((ext_vector_type(8))) __bf16 bf16x8;
typedef __attribute__((ext_vector_type(4))) __bf16 bf16x4;
typedef __attribute__((ext_vector_type(16))) float f32x16;

__device__ __forceinline__ float sigmoid_fast(float x) {
    float e = __expf(-x);
    return __builtin_amdgcn_rcpf(1.0f + e);
}

__device__ __forceinline__ void gload16(const void* g, const float* l) {
    __builtin_amdgcn_global_load_lds(
        (const __attribute__((address_space(1))) void*)g,
        (__attribute__((address_space(3))) void*)l, 16, 0, 0);
}

// ---------------- Pass 1: streaming pack — 512 blocks (long streams), contiguous writes ----------------
// block = (row r = bid>>4, seg s = bid&15); seg = 16384 floats. 4 rounds; per round 12
// contiguous float4 loads + row-major bf16 panel stores (512B runs per wave, no scatter).
__global__ __launch_bounds__(256) void cl_pack(const float* __restrict__ in1,
                                               const float* __restrict__ in2,
                                               const float* __restrict__ msk,
                                               float* __restrict__ ws) {
    const int tid = threadIdx.x;
    const int r   = blockIdx.x >> 4;
    const int s   = blockIdx.x & 15;

    const size_t base = (size_t)r * NF + (size_t)s * 16384;
    const float4* p1 = (const float4*)(in1 + base);
    const float4* p2 = (const float4*)(in2 + base);
    const float4* pm = (const float4*)(msk + base);
    char* panel1 = (char*)(ws + PAN1_OFF);
    char* panel2 = (char*)(ws + PAN2_OFF);

    float pos = 0.0f, q1 = 0.0f, q2 = 0.0f;

    #pragma unroll
    for (int rd = 0; rd < 4; ++rd) {
        const int o = rd * 1024;            // float4 offset of this round
        float4 A[4], B[4], M[4];
        #pragma unroll
        for (int j = 0; j < 4; ++j) A[j] = p1[o + j * 256 + tid];
        #pragma unroll
        for (int j = 0; j < 4; ++j) B[j] = p2[o + j * 256 + tid];
        #pragma unroll
        for (int j = 0; j < 4; ++j) M[j] = pm[o + j * 256 + tid];

        #pragma unroll
        for (int j = 0; j < 4; ++j) {
            const float* xa = (const float*)&A[j];
            const float* xb = (const float*)&B[j];
            const float* xm = (const float*)&M[j];
            bf16x4 ua, ub;
            #pragma unroll
            for (int e = 0; e < 4; ++e) {
                float sa = sigmoid_fast(xa[e]);
                float sb = sigmoid_fast(xb[e]);
                float d  = xm[e] * (sa - sb);
                pos = fmaf(d, d, pos);
                q1  = fmaf(sa, sa, q1);
                q2  = fmaf(sb, sb, q2);
                ua[e] = (__bf16)sa;
                ub[e] = (__bf16)sb;
            }
            const size_t k = base + (size_t)rd * 4096 + (size_t)j * 1024 + tid * 4;
            *(bf16x4*)(panel1 + k * 2) = ua;   // row-major, contiguous across lanes
            *(bf16x4*)(panel2 + k * 2) = ub;
        }
    }

    // ---- block reduction (all threads belong to row r), plain stores ----
    __shared__ float sred[4][3];
    #pragma unroll
    for (int off = 32; off; off >>= 1) {
        pos += __shfl_xor(pos, off);
        q1  += __shfl_xor(q1, off);
        q2  += __shfl_xor(q2, off);
    }
    if ((tid & 63) == 0) {
        sred[tid >> 6][0] = pos; sred[tid >> 6][1] = q1; sred[tid >> 6][2] = q2;
    }
    __syncthreads();
    if (tid == 0) {
        float* PQ = ws + PQ_OFF;
        PQ[r * 16 + s]        = sred[0][0] + sred[1][0] + sred[2][0] + sred[3][0];
        PQ[512 + r * 16 + s]  = sred[0][1] + sred[1][1] + sred[2][1] + sred[3][1];
        PQ[1024 + r * 16 + s] = sred[0][2] + sred[1][2] + sred[2][2] + sred[3][2];
    }
}

// ---------------- Pass 2: cross-GEMM; gather from the L3-warm row-major panel ----------------
// LDS per buffer (8KB): [a][row][8 chunks of 16B], chunk stored at (c ^ (row&7)).
// Same XOR involution as verified R9-R16 (linear LDS dest, swizzled source, swizzled read).
__global__ __launch_bounds__(256) void cl_gemm(const float* __restrict__ ws_ro,
                                               float* __restrict__ ws) {
    __shared__ float smem[4096];

    const int tid  = threadIdx.x;
    const int w    = tid >> 6;
    const int lane = tid & 63;
    const int r    = lane & 31;
    const int g    = lane >> 5;

    const char* pan[2] = {(const char*)(ws_ro + PAN1_OFF), (const char*)(ws_ro + PAN2_OFF)};
    const int kt0 = blockIdx.x * 4;

    f32x16 acc;
    #pragma unroll
    for (int k = 0; k < 16; ++k) acc[k] = 0.0f;

    auto stage = [&](int p, int kt) {
        #pragma unroll
        for (int m = 0; m < 2; ++m) {
            const int n   = w * 2 + m;            // 0..7: 1KB sub-block
            const int a   = n >> 2;               // array 0..1
            const int row = (n & 3) * 8 + (lane >> 3);
            const int sc  = (lane & 7) ^ (row & 7);
            gload16(pan[a] + ((size_t)row * NF + (size_t)kt * 64) * 2 + sc * 16,
                    smem + p * 2048 + n * 256);
        }
    };

    auto compute = [&](int p) {
        const int cs = (w * 2 + g) ^ (r & 7);     // wave w owns k-substep w
        const float* base = smem + p * 2048 + r * 32 + cs * 4;
        bf16x8 fa = *(const bf16x8*)(base);
        bf16x8 fb = *(const bf16x8*)(base + 1024);
        acc = __builtin_amdgcn_mfma_f32_32x32x16_bf16(fa, fb, acc, 0, 0, 0);
    };

    stage(0, kt0);
    __syncthreads();
    #pragma unroll
    for (int t = 0; t < 3; ++t) {
        stage((t + 1) & 1, kt0 + t + 1);
        compute(t & 1);
        __syncthreads();
    }
    compute(1);
    __syncthreads();

    const int col = lane & 31;
    const int rhi = (lane >> 5) * 4;
    #pragma unroll
    for (int reg = 0; reg < 16; ++reg) {
        const int row = (reg & 3) + 8 * (reg >> 2) + rhi;   // verified C/D mapping
        smem[w * 1024 + row * 32 + col] = acc[reg];
    }
    __syncthreads();

    float* P = ws + CREC_OFF + (size_t)blockIdx.x * CSTRIDE;
    for (int idx = tid; idx < 1024; idx += 256)
        P[idx] = smem[idx] + smem[1024 + idx] + smem[2048 + idx] + smem[3072 + idx];
}

__global__ __launch_bounds__(256) void cl_reduce(const float* __restrict__ ws_ro,
                                                 float* __restrict__ ws) {
    const int kg   = blockIdx.x >> 2;
    const int slot = (blockIdx.x & 3) * 256 + threadIdx.x;
    const float* base = ws_ro + CREC_OFF + (size_t)kg * 64 * CSTRIDE + slot;
    float s = 0.0f;
    #pragma unroll 8
    for (int k = 0; k < 64; ++k) s += base[(size_t)k * CSTRIDE];
    ws[WS2_OFF + kg * CSTRIDE + slot] = s;
}

__global__ __launch_bounds__(1024) void cl_final(const float* __restrict__ ws,
                                                 float* __restrict__ out) {
    __shared__ float s_loss[32];
    const int tid = threadIdx.x;
    const int i = tid >> 5, j = tid & 31;
    const float invN = 1.0f / (float)NF;

    float c = 0.0f, p = 0.0f, s1 = 0.0f, s2 = 0.0f;
    #pragma unroll
    for (int k = 0; k < NKG; ++k)
        c += ws[WS2_OFF + (size_t)k * CSTRIDE + i * 32 + j];
    const float* PQ = ws + PQ_OFF;
    #pragma unroll
    for (int k = 0; k < 16; ++k) {
        p  += PQ[i * 16 + k];
        s1 += PQ[512 + i * 16 + k];
        s2 += PQ[1024 + j * 16 + k];
    }

    float d = (s1 + s2 - 2.0f * c) * invN;
    float sim = (i == j) ? 0.0f : expf(-d * 10.0f);   // TAU = 0.1
    #pragma unroll
    for (int off = 16; off; off >>= 1) sim += __shfl_xor(sim, off);

    if (j == 0) {
        float sp = expf(-p * invN * 10.0f);
        s_loss[i] = -logf(sp / (sp + sim));
    }
    __syncthreads();
    if (tid == 0) {
        float t = 0.0f;
        #pragma unroll
        for (int k = 0; k < 32; ++k) t += s_loss[k];
        out[0] = t * (1.0f / 32.0f);
    }
}

extern "C" void kernel_launch(void* const* d_in, const int* in_sizes, int n_in,
                              void* d_out, int out_size, void* d_ws, size_t ws_size,
                              hipStream_t stream) {
    const float* in1 = (const float*)d_in[0];
    const float* in2 = (const float*)d_in[1];
    const float* msk = (const float*)d_in[2];
    float* out = (float*)d_out;
    float* ws  = (float*)d_ws;

    cl_pack  <<<512,  256, 0, stream>>>(in1, in2, msk, ws);
    cl_gemm  <<<1024, 256, 0, stream>>>(ws, ws);
    cl_reduce<<<64,   256, 0, stream>>>(ws, ws);
    cl_final <<<1,   1024, 0, stream>>>(ws, out);
}